// Round 12
// baseline (7220.613 us; speedup 1.0000x reference)
//
#include <hip/hip_runtime.h>
#include <math.h>

#define T_ALL 200

typedef __attribute__((ext_vector_type(8)))  short v8s;
typedef __attribute__((ext_vector_type(16))) float v16f;

__device__ __forceinline__ unsigned short f2bf(float f) {
    unsigned int u = __float_as_uint(f);
    u += 0x7FFF + ((u >> 16) & 1);          // round-to-nearest-even
    return (unsigned short)(u >> 16);
}
__device__ __forceinline__ float bf2f(unsigned short s) {
    return __uint_as_float(((unsigned int)s) << 16);
}
__device__ __forceinline__ float sigf(float x) { return 1.0f / (1.0f + expf(-x)); }

// device-coherent 16B fragment load: two 8B relaxed agent-scope atomic loads
// (emit sc0+sc1 -> bypass local L2, read the L3 coherence point).
__device__ __forceinline__ v8s ld16_coh(const unsigned short* p) {
    union { unsigned long long u[2]; v8s v; } c;
    c.u[0] = __hip_atomic_load((const unsigned long long*)p,
                               __ATOMIC_RELAXED, __HIP_MEMORY_SCOPE_AGENT);
    c.u[1] = __hip_atomic_load((const unsigned long long*)p + 1,
                               __ATOMIC_RELAXED, __HIP_MEMORY_SCOPE_AGENT);
    return c.v;
}

// ---- ws layout (bytes) ----
#define A_FRAGS   6656ULL
#define A_HI_OFF  0ULL
#define A_LO_OFF  (A_FRAGS * 1024ULL)                    //  6,815,744
#define X_HI_OFF  (2ULL * A_FRAGS * 1024ULL)             // 13,631,488
#define X_BYTES   (200ULL * 256 * 128 * 2)               // 13,107,200
#define X_LO_OFF  (X_HI_OFF + X_BYTES)
#define H_BYTES   (2ULL * 256 * 512 * 2)                 // 524,288 per plane
#define HHI0_OFF  (X_LO_OFF + X_BYTES)
#define HLO0_OFF  (HHI0_OFF + H_BYTES)
#define HHI1_OFF  (HLO0_OFF + H_BYTES)
#define HLO1_OFF  (HHI1_OFF + H_BYTES)
#define B0PK_OFF  (HLO1_OFF + H_BYTES)
#define B1PK_OFF  (B0PK_OFF + 8192ULL)
#define ARR_OFF   (B1PK_OFF + 8192ULL)
#define ARR_BYTES (201ULL * 8 * 32 * 4)                  // fresh line / (t, group)

// Pack W rows into MFMA 32x32x16 A-fragment order, bf16 hi/lo planes.
__global__ __launch_bounds__(64) void pack_w(
    const float* __restrict__ Wih0, const float* __restrict__ Whh0,
    const float* __restrict__ Wih1, const float* __restrict__ Whh1,
    unsigned short* __restrict__ Ahi, unsigned short* __restrict__ Alo)
{
    const int fi = blockIdx.x, lane = threadIdx.x;
    const float* W; int K, hg, c;
    if (fi < 512)       { W = Wih0; K = 128; hg = fi >> 3;          c = fi & 7;          }
    else if (fi < 2560) { W = Whh0; K = 512; hg = (fi - 512) >> 5;  c = (fi - 512) & 31; }
    else if (fi < 4608) { W = Wih1; K = 512; hg = (fi - 2560) >> 5; c = (fi - 2560) & 31;}
    else                { W = Whh1; K = 512; hg = (fi - 4608) >> 5; c = (fi - 4608) & 31;}
    const int m = lane & 31, half = lane >> 5;
    const int q = m & 3, hl = m >> 2;
    const int r = q * 512 + hg * 8 + hl;
    const int k0 = c * 16 + half * 8;
    const float* src = W + (size_t)r * K + k0;
    unsigned short* dh = Ahi + (size_t)fi * 512 + lane * 8;
    unsigned short* dl = Alo + (size_t)fi * 512 + lane * 8;
    #pragma unroll
    for (int j = 0; j < 8; ++j) {
        const float w = src[j];
        const unsigned short h = f2bf(w);
        dh[j] = h;
        dl[j] = f2bf(w - bf2f(h));
    }
}

// proposals [b][t][c] fp32 -> xHi/xLo [t][b][c] bf16
__global__ __launch_bounds__(256) void prep_x(const float* __restrict__ prop,
                                              unsigned short* __restrict__ xHi,
                                              unsigned short* __restrict__ xLo)
{
    const int t = blockIdx.x, b = threadIdx.x;
    const float* src = prop + ((size_t)b * 200 + t) * 128;
    unsigned short* dh = xHi + ((size_t)t * 256 + b) * 128;
    unsigned short* dl = xLo + ((size_t)t * 256 + b) * 128;
    #pragma unroll 4
    for (int c = 0; c < 128; ++c) {
        const float f = src[c];
        const unsigned short h = f2bf(f);
        dh[c] = h;
        dl[c] = f2bf(f - bf2f(h));
    }
}

// bias packs: bpk[hid] = float4 over gates (i,f,g,o)
__global__ __launch_bounds__(512) void pack_bias(
    const float* __restrict__ bih0, const float* __restrict__ bhh0,
    const float* __restrict__ bih1, const float* __restrict__ bhh1,
    float4* __restrict__ b0, float4* __restrict__ b1)
{
    const int hid = threadIdx.x;
    float4 u, v;
    u.x = bih0[hid] + bhh0[hid];
    u.y = bih0[512 + hid] + bhh0[512 + hid];
    u.z = bih0[1024 + hid] + bhh0[1024 + hid];
    u.w = bih0[1536 + hid] + bhh0[1536 + hid];
    v.x = bih1[hid] + bhh1[hid];
    v.y = bih1[512 + hid] + bhh1[512 + hid];
    v.z = bih1[1024 + hid] + bhh1[1024 + hid];
    v.w = bih1[1536 + hid] + bhh1[1536 + hid];
    b0[hid] = u; b1[hid] = v;
}

// PERSISTENT fused scan: all 201 supersteps in one dispatch. Weights (packed
// A-frags) use plain cached loads -> L2-resident for the whole scan (no
// dispatch invalidates). Only h crosses XCDs: written with relaxed
// agent-scope 8B atomic stores (write-through to L3), read with relaxed
// agent-scope 8B atomic loads (L2-bypass) — R5/R6-proven mechanics, no
// fences, no cache flushes. c-state lives in registers. Barrier: 8
// independent 64-block groups (one per 32-batch tile), fresh L3 line per
// (t, group), tid0 atomicAdd + s_sleep spin. 512 blocks x 256 threads
// (wave = matvec mv: 0=Wih0*x[t], 1=Whh0*h0[t-1], 2=Wih1*h0[t-1],
// 3=Whh1*h1[t-2]); residency: 512 blocks << capacity (~8 blocks/CU by
// threads at VGPR<=128, LDS 10KB) -> no deadlock.
__global__ __launch_bounds__(256) void lstm_scan(
    const unsigned short* __restrict__ Ahi, const unsigned short* __restrict__ Alo,
    const unsigned short* __restrict__ xHi, const unsigned short* __restrict__ xLo,
    unsigned short* __restrict__ hHi0, unsigned short* __restrict__ hLo0,
    unsigned short* __restrict__ hHi1, unsigned short* __restrict__ hLo1,
    const float4* __restrict__ b0pk, const float4* __restrict__ b1pk,
    int* __restrict__ arr)
{
    __shared__ float xch[2][32][32];                       // 8 KB C-tile exchange
    __shared__ __align__(16) unsigned short hst[2][2][32][8]; // [layer][plane][b][hl] 2KB
    const int tid  = threadIdx.x;
    const int mv   = tid >> 6, lane = tid & 63;
    const int f    = blockIdx.x;                  // 0..511
    const int hg   = (f & 7) * 8 + ((f >> 3) & 7);// 8 hgs per XCD (if %8 round-robin)
    const int bgt  = f >> 6;                      // 0..7 batch tile = barrier group
    const int ml   = lane & 31, half = lane >> 5;
    const int b    = bgt * 32 + ml;

    int fbase, nch;
    if (mv == 0)      { fbase = hg * 8;         nch = 8;  }
    else if (mv == 1) { fbase = 512 + hg * 32;  nch = 32; }
    else if (mv == 2) { fbase = 2560 + hg * 32; nch = 32; }
    else              { fbase = 4608 + hg * 32; nch = 32; }

    float4 bs[4];
    #pragma unroll
    for (int rq = 0; rq < 4; ++rq) {
        const int hid = hg * 8 + 2 * rq + half;
        bs[rq] = (mv == 1) ? b0pk[hid] : (mv == 3) ? b1pk[hid]
                                       : make_float4(0.f, 0.f, 0.f, 0.f);
    }
    float creg[4] = {0.f, 0.f, 0.f, 0.f};        // c-state in registers

    for (int t = 0; t <= T_ALL; ++t) {
        bool act; bool coh;
        const unsigned short *bh_p, *bl_p;
        if (mv == 0) {
            act = (t < T_ALL); coh = false;
            const size_t o = ((size_t)(act ? t : 0) * 256 + b) * 128;
            bh_p = xHi + o; bl_p = xLo + o;
        } else if (mv == 1) {
            act = (t >= 1 && t < T_ALL); coh = true;
            const size_t o = ((size_t)((t + 1) & 1) * 256 + b) * 512;
            bh_p = hHi0 + o; bl_p = hLo0 + o;
        } else if (mv == 2) {
            act = (t >= 1); coh = true;
            const size_t o = ((size_t)((t + 1) & 1) * 256 + b) * 512;
            bh_p = hHi0 + o; bl_p = hLo0 + o;
        } else {
            act = (t >= 2); coh = true;
            const size_t o = ((size_t)(t & 1) * 256 + b) * 512;  // (t-2)&1
            bh_p = hHi1 + o; bl_p = hLo1 + o;
        }

        v16f A0, A1;
        #pragma unroll
        for (int i = 0; i < 16; ++i) { A0[i] = 0.f; A1[i] = 0.f; }

        if (act) {
            #pragma unroll 8
            for (int c = 0; c < nch; ++c) {
                const v8s ah = *(const v8s*)(Ahi + ((size_t)(fbase + c)) * 512 + lane * 8);
                const v8s al = *(const v8s*)(Alo + ((size_t)(fbase + c)) * 512 + lane * 8);
                v8s bh, bl;
                if (coh) {
                    bh = ld16_coh(bh_p + c * 16 + half * 8);
                    bl = ld16_coh(bl_p + c * 16 + half * 8);
                } else {
                    bh = *(const v8s*)(bh_p + c * 16 + half * 8);
                    bl = *(const v8s*)(bl_p + c * 16 + half * 8);
                }
                A0 = __builtin_amdgcn_mfma_f32_32x32x16_bf16(ah, bh, A0, 0, 0, 0);
                A1 = __builtin_amdgcn_mfma_f32_32x32x16_bf16(al, bh, A1, 0, 0, 0);
                A0 = __builtin_amdgcn_mfma_f32_32x32x16_bf16(ah, bl, A0, 0, 0, 0);
                A1 = __builtin_amdgcn_mfma_f32_32x32x16_bf16(al, bl, A1, 0, 0, 0);
            }
        }
        float av[16];
        #pragma unroll
        for (int i = 0; i < 16; ++i) av[i] = A0[i] + A1[i];

        if (mv == 0 || mv == 2) {
            const int s = mv >> 1;
            #pragma unroll
            for (int r = 0; r < 16; ++r)
                xch[s][(r & 3) + 8 * (r >> 2) + 4 * half][ml] = av[r];
        }
        __syncthreads();

        if (mv == 1 && t < T_ALL) {           // layer-0 update: h0[t]
            #pragma unroll
            for (int rq = 0; rq < 4; ++rq) {
                const int hl = 2 * rq + half;
                float a[4];
                #pragma unroll
                for (int j = 0; j < 4; ++j)
                    a[j] = av[rq * 4 + j] + xch[0][j + 8 * rq + 4 * half][ml]
                         + ((const float*)&bs[rq])[j];
                const float ig = sigf(a[0]), fg = sigf(a[1]);
                const float gg = tanhf(a[2]), og = sigf(a[3]);
                creg[rq] = fg * creg[rq] + ig * gg;
                const float h = og * tanhf(creg[rq]);
                const unsigned short hh = f2bf(h);
                hst[0][0][ml][hl] = hh;
                hst[0][1][ml][hl] = f2bf(h - bf2f(hh));
            }
        }
        if (mv == 3 && t >= 1) {              // layer-1 update: h1[t-1]
            #pragma unroll
            for (int rq = 0; rq < 4; ++rq) {
                const int hl = 2 * rq + half;
                float a[4];
                #pragma unroll
                for (int j = 0; j < 4; ++j)
                    a[j] = av[rq * 4 + j] + xch[1][j + 8 * rq + 4 * half][ml]
                         + ((const float*)&bs[rq])[j];
                const float ig = sigf(a[0]), fg = sigf(a[1]);
                const float gg = tanhf(a[2]), og = sigf(a[3]);
                creg[rq] = fg * creg[rq] + ig * gg;
                const float h = og * tanhf(creg[rq]);
                const unsigned short hh = f2bf(h);
                hst[1][0][ml][hl] = hh;
                hst[1][1][ml][hl] = f2bf(h - bf2f(hh));
            }
        }
        __syncthreads();

        // cooperative device-coherent store of this block's h slice
        {
            const int layer = tid >> 7, plane = (tid >> 6) & 1;
            const int bl_ = (tid >> 1) & 31, hq = tid & 1;
            const bool doit = (layer == 0) ? (t < T_ALL) : (t >= 1);
            if (doit) {
                const unsigned long long val =
                    *(const unsigned long long*)&hst[layer][plane][bl_][hq * 4];
                unsigned short* basep = (layer == 0) ? (plane ? hLo0 : hHi0)
                                                     : (plane ? hLo1 : hHi1);
                const int slot = (layer == 0) ? (t & 1) : ((t + 1) & 1);
                unsigned long long* dst = (unsigned long long*)
                    (basep + ((size_t)slot * 256 + bgt * 32 + bl_) * 512 + hg * 8 + hq * 4);
                __hip_atomic_store(dst, val, __ATOMIC_RELAXED, __HIP_MEMORY_SCOPE_AGENT);
            }
        }

        if (t < T_ALL) {
            __threadfence_block();            // drain vmcnt (h stores complete at L3)
            __syncthreads();
            int* cp = arr + ((size_t)t * 8 + bgt) * 32;   // fresh line per (t,group)
            if (tid == 0) {
                __hip_atomic_fetch_add(cp, 1, __ATOMIC_RELAXED, __HIP_MEMORY_SCOPE_AGENT);
                while (__hip_atomic_load(cp, __ATOMIC_RELAXED, __HIP_MEMORY_SCOPE_AGENT) < 64)
                    __builtin_amdgcn_s_sleep(1);
            }
            __syncthreads();
        }
    }
}

// heads: base_feat = h1[:,199] (slot 1, hi+lo reconstruct) -> cls/bbox + 2 zeros
__global__ __launch_bounds__(64) void heads(
    const unsigned short* __restrict__ hHi1, const unsigned short* __restrict__ hLo1,
    const float4* __restrict__ clsW, const float* __restrict__ clsb,
    const float4* __restrict__ bbW, const float* __restrict__ bbb,
    float* __restrict__ out)
{
    const int b = blockIdx.x, j = threadIdx.x;
    const size_t off = (size_t)(256 + b) * 512;   // slot 1
    if (j < 42) {
        const float4* w = (j < 40) ? (clsW + (size_t)j * 128) : (bbW + (size_t)(j - 40) * 128);
        float acc = 0.f;
        #pragma unroll 4
        for (int k4 = 0; k4 < 128; ++k4) {
            const ushort4 hh = *(const ushort4*)(hHi1 + off + k4 * 4);
            const ushort4 hl = *(const ushort4*)(hLo1 + off + k4 * 4);
            const float4 wv = w[k4];
            acc += (bf2f(hh.x) + bf2f(hl.x)) * wv.x
                 + (bf2f(hh.y) + bf2f(hl.y)) * wv.y
                 + (bf2f(hh.z) + bf2f(hl.z)) * wv.z
                 + (bf2f(hh.w) + bf2f(hl.w)) * wv.w;
        }
        if (j < 40) out[(size_t)b * 40 + j] = acc + clsb[j];
        else        out[10240 + (size_t)b * 2 + (j - 40)] = acc + bbb[j - 40];
    }
    if (b == 0 && (j == 62 || j == 63)) out[10752 + (j - 62)] = 0.f;
}

extern "C" void kernel_launch(void* const* d_in, const int* in_sizes, int n_in,
                              void* d_out, int out_size, void* d_ws, size_t ws_size,
                              hipStream_t stream) {
    const float* proposals = (const float*)d_in[2];
    const float* Wih0 = (const float*)d_in[4];
    const float* Whh0 = (const float*)d_in[5];
    const float* bih0 = (const float*)d_in[6];
    const float* bhh0 = (const float*)d_in[7];
    const float* Wih1 = (const float*)d_in[8];
    const float* Whh1 = (const float*)d_in[9];
    const float* bih1 = (const float*)d_in[10];
    const float* bhh1 = (const float*)d_in[11];
    const float* clsW = (const float*)d_in[12];
    const float* clsb = (const float*)d_in[13];
    const float* bbW  = (const float*)d_in[14];
    const float* bbb  = (const float*)d_in[15];

    char* ws = (char*)d_ws;
    unsigned short* Ahi  = (unsigned short*)(ws + A_HI_OFF);
    unsigned short* Alo  = (unsigned short*)(ws + A_LO_OFF);
    unsigned short* xHi  = (unsigned short*)(ws + X_HI_OFF);
    unsigned short* xLo  = (unsigned short*)(ws + X_LO_OFF);
    unsigned short* hHi0 = (unsigned short*)(ws + HHI0_OFF);
    unsigned short* hLo0 = (unsigned short*)(ws + HLO0_OFF);
    unsigned short* hHi1 = (unsigned short*)(ws + HHI1_OFF);
    unsigned short* hLo1 = (unsigned short*)(ws + HLO1_OFF);
    float4* b0pk = (float4*)(ws + B0PK_OFF);
    float4* b1pk = (float4*)(ws + B1PK_OFF);
    int*    arr  = (int*)(ws + ARR_OFF);

    hipMemsetAsync(arr, 0, ARR_BYTES, stream);

    pack_w<<<(int)A_FRAGS, 64, 0, stream>>>(Wih0, Whh0, Wih1, Whh1, Ahi, Alo);
    prep_x<<<200, 256, 0, stream>>>(proposals, xHi, xLo);
    pack_bias<<<1, 512, 0, stream>>>(bih0, bhh0, bih1, bhh1, b0pk, b1pk);

    lstm_scan<<<512, 256, 0, stream>>>(Ahi, Alo, xHi, xLo,
                                       hHi0, hLo0, hHi1, hLo1,
                                       b0pk, b1pk, arr);

    heads<<<256, 64, 0, stream>>>(hHi1, hLo1, (const float4*)clsW, clsb,
                                  (const float4*)bbW, bbb, (float*)d_out);
}